// Round 16
// baseline (98.773 us; speedup 1.0000x reference)
//
#include <hip/hip_runtime.h>
#include <hip/hip_bf16.h>
#include <math.h>

using f32x4 = __attribute__((ext_vector_type(4))) float;
using s16x8 = __attribute__((ext_vector_type(8))) short;
using s16x4 = __attribute__((ext_vector_type(4))) short;

#define LOG2E 1.44269504f

__device__ __forceinline__ unsigned short f2bf(float f) {
  unsigned int u = __builtin_bit_cast(unsigned int, f);
  u += 0x7FFFu + ((u >> 16) & 1u);
  return (unsigned short)(u >> 16);
}
__device__ __forceinline__ float lrelu(float v) { return v > 0.f ? v : 0.01f * v; }

__device__ __forceinline__ unsigned packbf(float lo, float hi) {
  return __builtin_amdgcn_perm(__builtin_bit_cast(unsigned, hi),
                               __builtin_bit_cast(unsigned, lo), 0x07060302u);
}
__device__ __forceinline__ float redsum_lh(float x) {
  x += __shfl_xor(x, 16);
  x += __shfl_xor(x, 32);
  return x;
}

#define GLL16(src, dst)                                                        \
  __builtin_amdgcn_global_load_lds(                                            \
      (const __attribute__((address_space(1))) void*)(src),                    \
      (__attribute__((address_space(3))) void*)(dst), 16, 0, 0)

// ---------------------------------------------------------------------------
// Kernel 0: WT[w][k][c] = W_w[c][k]  (3x64x64 f32 into ws). grid 3, block 256.
// ---------------------------------------------------------------------------
__global__ __launch_bounds__(256) void k0_wt(const float* __restrict__ W1,
                                             const float* __restrict__ W2,
                                             const float* __restrict__ W3,
                                             float* __restrict__ WT) {
  __shared__ float s[64][65];
  const float* Ws[3] = {W1, W2, W3};
  const int w = blockIdx.x, t = threadIdx.x;
  for (int e = t; e < 4096; e += 256) s[e >> 6][e & 63] = Ws[w][e]; // s[c][k]
  __syncthreads();
  for (int e = t; e < 4096; e += 256) WT[w * 4096 + e] = s[e & 63][e >> 6];
}

// ---------------------------------------------------------------------------
// Kernel 1: x1t[n][c], x2t[n][c] (x2 pre-scaled by log2e), x3[c][n] (bf16).
// grid 512 (b*128 + nchunk32), block 512.  (R15-proven)
// ---------------------------------------------------------------------------
__global__ __launch_bounds__(512) void k1_conv3(
    const float* __restrict__ x, const float* __restrict__ WT,
    const float* __restrict__ b1, const float* __restrict__ b2,
    const float* __restrict__ b3,
    unsigned short* __restrict__ x1t, unsigned short* __restrict__ x2t,
    unsigned short* __restrict__ x3) {
  __shared__ float sB[64][33];
  const int t = threadIdx.x;
  const int b = blockIdx.x >> 7;
  const int n0 = (blockIdx.x & 127) << 5;
  const int c = t & 63, g = t >> 6; // wave g owns n' = g*4..g*4+3

  float y1[4], y2[4], y3[4];
  const float bb1 = b1[c], bb2 = b2[c], bb3 = b3[c];
#pragma unroll
  for (int j = 0; j < 4; ++j) { y1[j] = bb1; y2[j] = bb2; y3[j] = bb3; }

  const float* xb = x + ((size_t)b * 64) * 4096 + n0 + g * 4;
  const float* w1p = WT + c;
  const float* w2p = WT + 4096 + c;
  const float* w3p = WT + 8192 + c;
#pragma unroll 8
  for (int k = 0; k < 64; ++k) {
    const float w1 = w1p[k * 64], w2 = w2p[k * 64], w3 = w3p[k * 64];
    const float4 xv = *(const float4*)(xb + (size_t)k * 4096);
#pragma unroll
    for (int j = 0; j < 4; ++j) {
      const float xa = ((const float*)&xv)[j];
      y1[j] = __builtin_fmaf(w1, xa, y1[j]);
      y2[j] = __builtin_fmaf(w2, xa, y2[j]);
      y3[j] = __builtin_fmaf(w3, xa, y3[j]);
    }
  }
#pragma unroll
  for (int j = 0; j < 4; ++j) {
    const size_t n = (size_t)n0 + g * 4 + j;
    x1t[((size_t)b * 4096 + n) * 64 + c] = f2bf(lrelu(y1[j]));
    x2t[((size_t)b * 4096 + n) * 64 + c] = f2bf(lrelu(y2[j]) * LOG2E);
    sB[c][g * 4 + j] = lrelu(y3[j]);
  }
  __syncthreads();
  {
    const int c2 = t >> 3, q = t & 7;
    s16x4 v;
#pragma unroll
    for (int jj = 0; jj < 4; ++jj) v[jj] = (short)f2bf(sB[c2][q * 4 + jj]);
    *(s16x4*)(x3 + ((size_t)b * 64 + c2) * 4096 + n0 + q * 4) = v;
  }
}

// ---------------------------------------------------------------------------
// Kernel 2: flash attention, FREE-RUNNING wave-private pipeline (R10 scheme)
// with 64m/wave (2x staging reuse via registers) + fused epilogue.
// grid 256 = (b:4, mtile:64 [64m]). block 512 = 8 waves; wave w owns ALL 64m
// and n in [w*512,(w+1)*512): 16 steps of 32n. Per-wave dbuf K/V 16KB
// (R14-proven layouts). NO loop barriers: per step, vmcnt(8) [tile j landed,
// j+1 in flight] -> ds_read frags -> lgkmcnt(0) -> issue tile j+2 into this
// buffer -> setprio(1) MFMA cluster setprio(0). Transpose-free PV (R12).
// Epilogue: 2 chunks of 32m: cO (R13 swizzle) over dead staging -> 8-wave
// merge -> attnS -> W4 conv + lrelu + residual.
// LDS: staging 8x16KB = 131072 | W4 [64][68] f32 @131072 | sL [8][64] @148480.
// Epilogue overlay: cO 8x8KB @0, attnS [64][33] f32 @65536. SMSZ=150528.
// ---------------------------------------------------------------------------
#define W4OFF 131072
#define ATOFF 65536
#define SLOFF 148480
#define SMSZ 150528

__global__ __launch_bounds__(512, 2) void k2_attn_fused(
    const unsigned short* __restrict__ x1t,
    const unsigned short* __restrict__ x2t,
    const unsigned short* __restrict__ x3,
    const float* __restrict__ W4, const float* __restrict__ b4,
    const float* __restrict__ x, float* __restrict__ out) {
  __shared__ __align__(16) char SM[SMSZ];
  char* smB = (char*)SM;

  const int t = threadIdx.x;
  const int wave = t >> 6, lane = t & 63;
  const int l15 = lane & 15, lh = lane >> 4;
  const int b = blockIdx.x >> 6;
  const int m0 = (blockIdx.x & 63) << 6;
  const int nb = wave * 512; // wave's private n-slice: 16 steps of 32n

  const char* x1B = (const char*)(x1t + (size_t)b * 4096 * 64); // [n][c] 128B rows
  const char* x3B = (const char*)(x3 + (size_t)b * 64 * 4096);  // [c][n] 8192B rows
  const unsigned short* x2b = x2t + (size_t)b * 4096 * 64;

  { // W4 -> LDS transposed (disjoint region; consumed only in epilogue)
    float* Wt4 = (float*)(smB + W4OFF);
    for (int e = t; e < 4096; e += 512) Wt4[(e & 63) * 68 + (e >> 6)] = W4[e];
  }

  // wave-private staging: K0 @0, K1 @4096, V0 @8192, V1 @12288
  char* wbase = smB + wave * 16384;

  // staging source offsets (R14-proven pre-swizzle), 4 GLL shares each
  int kSrc[4], vSrc[4];
#pragma unroll
  for (int i = 0; i < 4; ++i) {
    const int o = i * 1024 + lane * 16;
    const int n = o >> 7, cb = (o & 127) ^ ((n & 7) << 4);
    kSrc[i] = n * 128 + cb; // + nt*128
    const int ch = o >> 7, rem = (o & 127) ^ ((ch & 7) << 4);
    vSrc[i] = (ch * 2 + (rem >> 6)) * 8192 + (rem & 63); // + nt*2
  }

  // Q fragments (B-operand), persistent: 4 groups of 16 m (64m total)
  s16x8 qf[4][2];
#pragma unroll
  for (int q2 = 0; q2 < 4; ++q2) {
    const unsigned short* qp = x2b + (size_t)(m0 + q2 * 16 + l15) * 64 + lh * 8;
    qf[q2][0] = *(const s16x8*)qp;
    qf[q2][1] = *(const s16x8*)(qp + 32);
  }

  f32x4 O[4][4];
#pragma unroll
  for (int q2 = 0; q2 < 4; ++q2)
#pragma unroll
    for (int s = 0; s < 4; ++s) O[q2][s] = (f32x4){0.f, 0.f, 0.f, 0.f};
  float l_part[4] = {0.f, 0.f, 0.f, 0.f};

  const int swzK = (l15 & 7) << 4;
  const int swzV = ((l15 >> 1) & 7) << 4;

  // prologue: stage tile 0 -> buf0, tile 1 -> buf1 (8 GLL each; 16 in flight)
#pragma unroll
  for (int i = 0; i < 4; ++i) {
    GLL16(x1B + (size_t)nb * 128 + kSrc[i], wbase + i * 1024);
    GLL16(x3B + (size_t)nb * 2 + vSrc[i], wbase + 8192 + i * 1024);
  }
#pragma unroll
  for (int i = 0; i < 4; ++i) {
    const int n1 = nb + 32;
    GLL16(x1B + (size_t)n1 * 128 + kSrc[i], wbase + 4096 + i * 1024);
    GLL16(x3B + (size_t)n1 * 2 + vSrc[i], wbase + 12288 + i * 1024);
  }

#pragma unroll
  for (int j = 0; j < 16; ++j) {
    // ---- tile j staged? (8 newest = tile j+1 stay in flight; never drain)
    if (j < 15) {
      asm volatile("s_waitcnt vmcnt(8)" ::: "memory");
    } else {
      asm volatile("s_waitcnt vmcnt(0)" ::: "memory");
    }
    __builtin_amdgcn_sched_barrier(0);
    char* Kbuf = wbase + (j & 1) * 4096;
    char* Vbuf = wbase + 8192 + (j & 1) * 4096;
    // ---- fragment reads (wave-private, no barrier)
    s16x8 kf[2][2];
#pragma unroll
    for (int s2 = 0; s2 < 2; ++s2) {
      const char* kp = Kbuf + (s2 * 16 + l15) * 128;
      kf[s2][0] = *(const s16x8*)(kp + ((lh * 16) ^ swzK));
      kf[s2][1] = *(const s16x8*)(kp + ((lh * 16 + 64) ^ swzK));
    }
    s16x8 vf[4];
#pragma unroll
    for (int s = 0; s < 4; ++s) {
      const int c = s * 16 + l15;
      const char* vrow = Vbuf + (c >> 1) * 128;
      const int nat_e = (c & 1) * 64 + lh * 8;
      const s16x4 ve = *(const s16x4*)(vrow + (nat_e ^ swzV));
      const s16x4 vo = *(const s16x4*)(vrow + ((nat_e + 32) ^ swzV));
#pragma unroll
      for (int e = 0; e < 4; ++e) { vf[s][e] = ve[e]; vf[s][e + 4] = vo[e]; }
    }
    // ---- my reads retired -> safe to overwrite this buffer with tile j+2
    asm volatile("s_waitcnt lgkmcnt(0)" ::: "memory");
    __builtin_amdgcn_sched_barrier(0);
    if (j < 14) {
      const int nt = nb + (j + 2) * 32;
#pragma unroll
      for (int i = 0; i < 4; ++i) {
        GLL16(x1B + (size_t)nt * 128 + kSrc[i], Kbuf + i * 1024);
        GLL16(x3B + (size_t)nt * 2 + vSrc[i], Vbuf + i * 1024);
      }
    }
    __builtin_amdgcn_sched_barrier(0);
    // ---- QK -> exp2 -> transpose-free PV, 4 m-groups (T5 setprio)
    __builtin_amdgcn_s_setprio(1);
#pragma unroll
    for (int q2 = 0; q2 < 4; ++q2) {
      f32x4 ze = {0.f, 0.f, 0.f, 0.f};
      ze = __builtin_amdgcn_mfma_f32_16x16x32_bf16(kf[0][0], qf[q2][0], ze, 0, 0, 0);
      ze = __builtin_amdgcn_mfma_f32_16x16x32_bf16(kf[0][1], qf[q2][1], ze, 0, 0, 0);
      f32x4 zo = {0.f, 0.f, 0.f, 0.f};
      zo = __builtin_amdgcn_mfma_f32_16x16x32_bf16(kf[1][0], qf[q2][0], zo, 0, 0, 0);
      zo = __builtin_amdgcn_mfma_f32_16x16x32_bf16(kf[1][1], qf[q2][1], zo, 0, 0, 0);
      const float e0 = __builtin_amdgcn_exp2f(ze[0]);
      const float e1 = __builtin_amdgcn_exp2f(ze[1]);
      const float e2 = __builtin_amdgcn_exp2f(ze[2]);
      const float e3 = __builtin_amdgcn_exp2f(ze[3]);
      const float o0 = __builtin_amdgcn_exp2f(zo[0]);
      const float o1 = __builtin_amdgcn_exp2f(zo[1]);
      const float o2 = __builtin_amdgcn_exp2f(zo[2]);
      const float o3 = __builtin_amdgcn_exp2f(zo[3]);
      l_part[q2] += ((e0 + e1) + (e2 + e3)) + ((o0 + o1) + (o2 + o3));
      int4 pw = {(int)packbf(e0, e1), (int)packbf(e2, e3),
                 (int)packbf(o0, o1), (int)packbf(o2, o3)};
      s16x8 pf = __builtin_bit_cast(s16x8, pw);
#pragma unroll
      for (int s = 0; s < 4; ++s)
        O[q2][s] = __builtin_amdgcn_mfma_f32_16x16x32_bf16(vf[s], pf, O[q2][s], 0, 0, 0);
    }
    __builtin_amdgcn_s_setprio(0);
  }

  // ---- epilogue: all-wave merge in 2 chunks of 32m over dead staging LDS
  __syncthreads();
  float* sLf = (float*)(smB + SLOFF); // [8][64]
#pragma unroll
  for (int q2 = 0; q2 < 4; ++q2) {
    const float l = redsum_lh(l_part[q2]);
    if (lh == 0) sLf[wave * 64 + q2 * 16 + l15] = l;
  }
  const int m = t & 31, cg = t >> 5; // reducer/conv role: m(32) x cg(16: 4ch)
  float* attnS = (float*)(smB + ATOFF);    // [64][33]
  const float* Wt4 = (const float*)(smB + W4OFF);
#pragma unroll
  for (int chk = 0; chk < 2; ++chk) {
    // write cO for q2 = 2*chk, 2*chk+1 (R13-swizzled, 8KB/wave)
#pragma unroll
    for (int qh = 0; qh < 2; ++qh) {
      const int q2 = chk * 2 + qh;
      const int m32 = qh * 16 + l15;
#pragma unroll
      for (int s = 0; s < 4; ++s) {
        const int cb = s * 64 + lh * 16;
        *(f32x4*)(smB + wave * 8192 + m32 * 256 + (cb ^ ((m32 & 7) << 4))) = O[q2][s];
      }
    }
    __syncthreads();
    // reduce 8 waves
    float den = 0.f;
    f32x4 num = {0.f, 0.f, 0.f, 0.f};
#pragma unroll
    for (int w = 0; w < 8; ++w) {
      den += sLf[w * 64 + chk * 32 + m];
      num += *(const f32x4*)(smB + w * 8192 + m * 256 + ((cg * 16) ^ ((m & 7) << 4)));
    }
    const float inv = 1.f / den;
    __syncthreads(); // cO reads done; attnS free
#pragma unroll
    for (int jj = 0; jj < 4; ++jj) attnS[(cg * 4 + jj) * 33 + m] = num[jj] * inv;
    __syncthreads();
    // conv4 + lrelu + residual for this 32m chunk
    const int co0 = cg * 4;
    float acc[4];
#pragma unroll
    for (int ci = 0; ci < 4; ++ci) acc[ci] = b4[co0 + ci];
    for (int k = 0; k < 64; ++k) {
      const float a = attnS[k * 33 + m];
      const float4 wv = *(const float4*)&Wt4[k * 68 + co0];
#pragma unroll
      for (int ci = 0; ci < 4; ++ci)
        acc[ci] = __builtin_fmaf(((const float*)&wv)[ci], a, acc[ci]);
    }
#pragma unroll
    for (int ci = 0; ci < 4; ++ci) {
      const size_t idx = ((size_t)b * 64 + co0 + ci) * 4096 + m0 + chk * 32 + m;
      out[idx] = lrelu(acc[ci]) + x[idx];
    }
  }
}

extern "C" void kernel_launch(void* const* d_in, const int* in_sizes, int n_in,
                              void* d_out, int out_size, void* d_ws, size_t ws_size,
                              hipStream_t stream) {
  const float* x = (const float*)d_in[0];
  const float* W1 = (const float*)d_in[1];
  const float* b1 = (const float*)d_in[2];
  const float* W2 = (const float*)d_in[3];
  const float* b2 = (const float*)d_in[4];
  const float* W3 = (const float*)d_in[5];
  const float* b3 = (const float*)d_in[6];
  const float* W4 = (const float*)d_in[7];
  const float* b4 = (const float*)d_in[8];
  float* out = (float*)d_out;

  const size_t planes = (size_t)4 * 4096 * 64; // 1M bf16 elems each
  unsigned short* x1t = (unsigned short*)d_ws;
  unsigned short* x2t = x1t + planes;
  unsigned short* x3 = x2t + planes;
  float* WT = (float*)(x3 + planes); // 3*4096 f32

  hipLaunchKernelGGL(k0_wt, dim3(3), dim3(256), 0, stream, W1, W2, W3, WT);
  hipLaunchKernelGGL(k1_conv3, dim3(512), dim3(512), 0, stream,
                     x, WT, b1, b2, b3, x1t, x2t, x3);
  hipLaunchKernelGGL(k2_attn_fused, dim3(256), dim3(512), 0, stream,
                     x1t, x2t, x3, W4, b4, x, out);
}

// Round 17
// 50.989 us; speedup vs baseline: 1.9372x; 1.9372x over previous
//
#include <hip/hip_runtime.h>
#include <hip/hip_bf16.h>
#include <math.h>

using f32x4 = __attribute__((ext_vector_type(4))) float;
using s16x8 = __attribute__((ext_vector_type(8))) short;
using s16x4 = __attribute__((ext_vector_type(4))) short;

#define LOG2E 1.44269504f

__device__ __forceinline__ unsigned short f2bf(float f) {
  unsigned int u = __builtin_bit_cast(unsigned int, f);
  u += 0x7FFFu + ((u >> 16) & 1u);
  return (unsigned short)(u >> 16);
}
__device__ __forceinline__ float lrelu(float v) { return v > 0.f ? v : 0.01f * v; }

// pack two f32 -> one u32 of 2 bf16 (truncation; bias cancels in softmax ratio)
__device__ __forceinline__ unsigned packbf(float lo, float hi) {
  return __builtin_amdgcn_perm(__builtin_bit_cast(unsigned, hi),
                               __builtin_bit_cast(unsigned, lo), 0x07060302u);
}
__device__ __forceinline__ float redsum_lh(float x) {
  x += __shfl_xor(x, 16);
  x += __shfl_xor(x, 32);
  return x;
}
// bit-transposition (lane-bit X <-> register-pair bit). R7/R9-PROVEN.
__device__ __forceinline__ void xswap(unsigned& A, unsigned& B, int X) {
  const int lane = (int)(threadIdx.x & 63);
  unsigned sel = (lane & X) ? A : B;
  unsigned ex = (unsigned)__shfl_xor((int)sel, X);
  A = (lane & X) ? ex : A;
  B = (lane & X) ? B : ex;
}

#define GLL16(src, dst)                                                        \
  __builtin_amdgcn_global_load_lds(                                            \
      (const __attribute__((address_space(1))) void*)(src),                    \
      (__attribute__((address_space(3))) void*)(dst), 16, 0, 0)

// ---------------------------------------------------------------------------
// Kernel 1 (MFMA): x1t[n][c], x2t[n][c] (x2 pre-scaled by log2e), x3[c][n].
// grid 256 = (b:4, ntile:64 [64n]), block 256 = 4 waves (wave = 16n strip).
// Per block: stage W1..3 -> bf16 LDS (XOR-swizzled, k2-proven pattern) and
// X^T tile (64n x 64k bf16); 24 MFMAs/wave with bias in C-operand.
// Layout convention (R1-proven): A row=l15/k=lh*8+i; B col=l15; D row=lh*4+r.
// LDS: XT 8KB @0 | Wb 24KB @8192 | sX3 [64][72] 9216B @32768. SM 41984.
// ---------------------------------------------------------------------------
#define K1_W 8192
#define K1_X3 32768
#define K1_SM 41984

__global__ __launch_bounds__(256) void k1_conv3(
    const float* __restrict__ x,
    const float* __restrict__ W1, const float* __restrict__ b1,
    const float* __restrict__ W2, const float* __restrict__ b2,
    const float* __restrict__ W3, const float* __restrict__ b3,
    unsigned short* __restrict__ x1t, unsigned short* __restrict__ x2t,
    unsigned short* __restrict__ x3) {
  __shared__ __align__(16) char SM[K1_SM];
  char* smB = (char*)SM;
  const int t = threadIdx.x;
  const int b = blockIdx.x >> 6;
  const int n0 = (blockIdx.x & 63) << 6;
  const int lane = t & 63, wave = t >> 6; // wave = nj (16-n strip)
  const int l15 = lane & 15, lh = lane >> 4;
  const int swz = (l15 & 7) << 4;

  // ---- stage W1..3 -> Wb bf16, XOR-swizzled rows (one-time)
  const float* Ws[3] = {W1, W2, W3};
  char* Wb = smB + K1_W;
#pragma unroll
  for (int w = 0; w < 3; ++w)
#pragma unroll
    for (int it = 0; it < 4; ++it) {
      const int c = t >> 2, k4 = (t & 3) * 16 + it * 4;
      const float4 wv = *(const float4*)(Ws[w] + c * 64 + k4);
      char* dst = Wb + w * 8192 + c * 128 + ((k4 * 2) ^ ((c & 7) << 4));
      *(unsigned*)dst = packbf(wv.x, wv.y);
      *(unsigned*)(dst + 4) = packbf(wv.z, wv.w);
    }
  // ---- stage XT[n][k] bf16, XOR-swizzled (transpose of x tile)
  char* XT = smB;
#pragma unroll
  for (int it = 0; it < 4; ++it) {
    const int k = (t >> 4) + it * 16, n4 = (t & 15) * 4;
    const float4 xv = *(const float4*)(x + ((size_t)b * 64 + k) * 4096 + n0 + n4);
#pragma unroll
    for (int j = 0; j < 4; ++j) {
      const int n = n4 + j;
      *(unsigned short*)(XT + n * 128 + ((k * 2) ^ ((n & 7) << 4))) =
          f2bf(((const float*)&xv)[j]);
    }
  }
  __syncthreads();

  // ---- B-frags for my n-strip (n = wave*16 + l15)
  s16x8 bf0, bf1;
  {
    const char* xr = XT + (wave * 16 + l15) * 128;
    bf0 = *(const s16x8*)(xr + ((lh * 16) ^ swz));
    bf1 = *(const s16x8*)(xr + ((lh * 16 + 64) ^ swz));
  }
  // ---- 3 convs x 4 c-tiles: MFMA (bias in C) -> lrelu -> store
  char* sX3 = smB + K1_X3; // [64][72] bf16
#pragma unroll
  for (int w = 0; w < 3; ++w) {
    const float* bb = (w == 0) ? b1 : (w == 1) ? b2 : b3;
#pragma unroll
    for (int ci = 0; ci < 4; ++ci) {
      f32x4 acc = *(const f32x4*)(bb + ci * 16 + lh * 4); // C = bias (row=lh*4+r)
      const char* wr = Wb + w * 8192 + (ci * 16 + l15) * 128;
      const s16x8 af0 = *(const s16x8*)(wr + ((lh * 16) ^ swz));
      const s16x8 af1 = *(const s16x8*)(wr + ((lh * 16 + 64) ^ swz));
      acc = __builtin_amdgcn_mfma_f32_16x16x32_bf16(af0, bf0, acc, 0, 0, 0);
      acc = __builtin_amdgcn_mfma_f32_16x16x32_bf16(af1, bf1, acc, 0, 0, 0);
      float v[4];
#pragma unroll
      for (int r = 0; r < 4; ++r) v[r] = lrelu(acc[r]);
      if (w == 1)
#pragma unroll
        for (int r = 0; r < 4; ++r) v[r] *= LOG2E;
      if (w < 2) {
        // lane holds 4 consecutive c at n = n0 + wave*16 + l15 -> 8B store
        unsigned pk[2] = {packbf(v[0], v[1]), packbf(v[2], v[3])};
        unsigned short* base = (w ? x2t : x1t);
        unsigned short* dst =
            base + ((size_t)b * 4096 + n0 + wave * 16 + l15) * 64 + ci * 16 + lh * 4;
        *(uint2*)dst = *(const uint2*)pk;
      } else {
#pragma unroll
        for (int r = 0; r < 4; ++r)
          *(unsigned short*)(sX3 + (ci * 16 + lh * 4 + r) * 144 +
                             (wave * 16 + l15) * 2) = f2bf(v[r]);
      }
    }
  }
  __syncthreads();
  // ---- x3 coalesced store: thread -> row c2 = t>>2, 16n chunk q = t&3
  {
    const int c2 = t >> 2, q = t & 3;
    const s16x8 v0 = *(const s16x8*)(sX3 + c2 * 144 + q * 32);
    const s16x8 v1 = *(const s16x8*)(sX3 + c2 * 144 + q * 32 + 16);
    unsigned short* dst = x3 + ((size_t)b * 64 + c2) * 4096 + n0 + q * 16;
    *(s16x8*)dst = v0;
    *(s16x8*)(dst + 8) = v1;
  }
}

// ---------------------------------------------------------------------------
// Kernel 2: R9-PROVEN kernel, VERBATIM (43.4 us measured, absmax 0.03125).
// flash attention (no-max exp2) + merge + conv4 + residual.
// grid 256 = (b, mtile64). block 1024 = 16 waves = msub(2: 32m) x split(8: 512n).
// K,V DOUBLE-buffered; ONE barrier per step. P transposed via xswap butterfly.
// l-reduction deferred to epilogue.
// ---------------------------------------------------------------------------
#define KOFF 0
#define VOFF 65536
#define W4OFF 131072
#define SLOFF 148480
#define SMSZ 150528

__global__ __launch_bounds__(1024) void k2_attn_fused(
    const unsigned short* __restrict__ x1t,
    const unsigned short* __restrict__ x2t,
    const unsigned short* __restrict__ x3,
    const float* __restrict__ W4, const float* __restrict__ b4,
    const float* __restrict__ x, float* __restrict__ out) {
  __shared__ __align__(16) char SM[SMSZ];
  char* smB = (char*)SM;

  const int t = threadIdx.x;
  const int wave = t >> 6, lane = t & 63;
  const int l15 = lane & 15, lh = lane >> 4;
  const int msub = wave & 1, split = wave >> 1; // split 0..7
  const int b = blockIdx.x >> 6;
  const int m0 = (blockIdx.x & 63) << 6;
  const int nb = split * 512;

  const char* x1B = (const char*)(x1t + (size_t)b * 4096 * 64); // [n][c] rows 128B
  const char* x3B = (const char*)(x3 + (size_t)b * 64 * 4096);  // [c][n] rows 8192B
  const unsigned short* x2b = x2t + (size_t)b * 4096 * 64;

  // W4 -> LDS transposed (region disjoint from K/V; loaded once)
  {
    float* Wt4 = (float*)(smB + W4OFF);
    for (int e = t; e < 4096; e += 1024) Wt4[(e & 63) * 68 + (e >> 6)] = W4[e];
  }

  // staging offsets: pre-swizzled global source, linear LDS dest (base, no p)
  int kSrcOff[2], vSrcOff[2];
  char *kDst[2], *vDst[2];
#pragma unroll
  for (int i = 0; i < 2; ++i) {
    const int o = msub * 2048 + i * 1024 + lane * 16;
    {
      const int n = o >> 7, cb = (o & 127) ^ ((n & 7) << 4);
      kSrcOff[i] = n * 128 + cb;
      kDst[i] = smB + KOFF + split * 4096 + msub * 2048 + i * 1024;
    }
    {
      const int ch = o >> 7, rem = (o & 127) ^ ((ch & 7) << 4);
      vSrcOff[i] = (ch * 2 + (rem >> 6)) * 8192 + (rem & 63);
      vDst[i] = smB + VOFF + split * 4096 + msub * 2048 + i * 1024;
    }
  }

  // Q fragments (B-operand), persistent
  s16x8 qf[2][2];
#pragma unroll
  for (int q2 = 0; q2 < 2; ++q2) {
    const unsigned short* qp = x2b + (size_t)(m0 + msub * 32 + q2 * 16 + l15) * 64 + lh * 8;
    qf[q2][0] = *(const s16x8*)qp;
    qf[q2][1] = *(const s16x8*)(qp + 32);
  }

  f32x4 O[2][4];
#pragma unroll
  for (int q2 = 0; q2 < 2; ++q2)
#pragma unroll
    for (int s = 0; s < 4; ++s) O[q2][s] = (f32x4){0.f, 0.f, 0.f, 0.f};
  float l_part[2] = {0.f, 0.f};

  const int swzK = (l15 & 7) << 4;
  const int swzV = ((l15 >> 1) & 7) << 4;

  // prologue: stage tile 0 into buffer 0
#pragma unroll
  for (int i = 0; i < 2; ++i) {
    GLL16(x1B + (size_t)nb * 128 + kSrcOff[i], kDst[i]);
    GLL16(x3B + (size_t)nb * 2 + vSrcOff[i], vDst[i]);
  }
  __syncthreads();

  for (int j = 0; j < 16; ++j) {
    const int p = j & 1;
    // ---- stage next tile into the other buffer (drained by this step's barrier)
    if (j < 15) {
      const int nstep = nb + (j + 1) * 32;
      const int po = (p ^ 1) * 32768;
#pragma unroll
      for (int i = 0; i < 2; ++i) {
        GLL16(x1B + (size_t)nstep * 128 + kSrcOff[i], kDst[i] + po);
        GLL16(x3B + (size_t)nstep * 2 + vSrcOff[i], vDst[i] + po);
      }
    }
    // ---- LDS fragment reads (K + V for this tile, buffer p)
    s16x8 kf[2][2], vf[4];
#pragma unroll
    for (int s2 = 0; s2 < 2; ++s2) {
      const char* kp = smB + KOFF + p * 32768 + split * 4096 + (s2 * 16 + l15) * 128;
      kf[s2][0] = *(const s16x8*)(kp + ((lh * 16) ^ swzK));
      kf[s2][1] = *(const s16x8*)(kp + ((lh * 16 + 64) ^ swzK));
    }
    const char* vp = smB + VOFF + p * 32768 + split * 4096;
#pragma unroll
    for (int s = 0; s < 4; ++s) {
      const int c = s * 16 + l15;
      vf[s] = *(const s16x8*)(vp + (c >> 1) * 128 + (((c & 1) * 64 + lh * 16) ^ swzV));
    }
    // ---- QK: S[q2][s2], n on (s2, lh, r), m on l15
    f32x4 S[2][2];
#pragma unroll
    for (int q2 = 0; q2 < 2; ++q2)
#pragma unroll
      for (int s2 = 0; s2 < 2; ++s2) {
        f32x4 z = {0.f, 0.f, 0.f, 0.f};
        z = __builtin_amdgcn_mfma_f32_16x16x32_bf16(kf[s2][0], qf[q2][0], z, 0, 0, 0);
        S[q2][s2] = __builtin_amdgcn_mfma_f32_16x16x32_bf16(kf[s2][1], qf[q2][1], z, 0, 0, 0);
      }
    // ---- softmax without max subtraction: p = exp2(S); defer l-reduction
    s16x8 pf[2];
#pragma unroll
    for (int q2 = 0; q2 < 2; ++q2) {
      float pr[2][4];
      float ts = 0.f;
#pragma unroll
      for (int s2 = 0; s2 < 2; ++s2)
#pragma unroll
        for (int r = 0; r < 4; ++r) {
          pr[s2][r] = __builtin_amdgcn_exp2f(S[q2][s2][r]);
          ts += pr[s2][r];
        }
      l_part[q2] += ts;
      unsigned u00 = packbf(pr[0][0], pr[0][1]), u01 = packbf(pr[0][2], pr[0][3]);
      unsigned u10 = packbf(pr[1][0], pr[1][1]), u11 = packbf(pr[1][2], pr[1][3]);
      xswap(u00, u10, 32); xswap(u01, u11, 32); // (L5 <-> W1)
      xswap(u00, u10, 16); xswap(u01, u11, 16); // (L4 <-> W1)
      int4 w = {(int)u00, (int)u01, (int)u10, (int)u11};
      pf[q2] = __builtin_bit_cast(s16x8, w);
    }
    // ---- PV
#pragma unroll
    for (int q2 = 0; q2 < 2; ++q2)
#pragma unroll
      for (int s = 0; s < 4; ++s)
        O[q2][s] = __builtin_amdgcn_mfma_f32_16x16x32_bf16(vf[s], pf[q2], O[q2][s], 0, 0, 0);
    __syncthreads(); // one barrier/step: syncs reads of buf p + drains staging
  }

  // ---- epilogue 1: l reduce (once) + publish fp32 partials over dead K/V
  float* cOf = (float*)smB;           // [16][32][64] = 128KB, overlays K+V
  float* sLf = (float*)(smB + SLOFF); // [16][32]
#pragma unroll
  for (int q2 = 0; q2 < 2; ++q2) {
    const float l = redsum_lh(l_part[q2]);
    const int m32 = q2 * 16 + l15;
    if (lh == 0) sLf[wave * 32 + m32] = l;
#pragma unroll
    for (int s = 0; s < 4; ++s)
      *(f32x4*)(cOf + wave * 2048 + m32 * 64 + s * 16 + lh * 4) = O[q2][s];
  }
  __syncthreads();

  // ---- epilogue 2: merge 8 splits (plain sums). thread -> m=t&63, cq=t>>6
  const int mloc = t & 63, cq = t >> 6;
  const int msub2 = mloc >> 5, m32b = mloc & 31;
  float den = 0.f, num[4] = {0.f, 0.f, 0.f, 0.f};
#pragma unroll
  for (int s2 = 0; s2 < 8; ++s2) {
    const int w = msub2 + 2 * s2;
    den += sLf[w * 32 + m32b];
    const f32x4 cv = *(const f32x4*)(cOf + w * 2048 + m32b * 64 + cq * 4);
#pragma unroll
    for (int jj = 0; jj < 4; ++jj) num[jj] += cv[jj];
  }
  const float inv = 1.f / den;
  __syncthreads(); // cO reads done -> safe to overlay attnS
  float* attnS = (float*)smB; // [64][65]
#pragma unroll
  for (int jj = 0; jj < 4; ++jj) attnS[(cq * 4 + jj) * 65 + mloc] = num[jj] * inv;
  __syncthreads();

  // ---- epilogue 3: out = lrelu(W4 @ attn + b4) + x
  const float* Wt4 = (const float*)(smB + W4OFF); // [64][68]
  const int co0 = cq * 4;
  float acc[4];
#pragma unroll
  for (int ci = 0; ci < 4; ++ci) acc[ci] = b4[co0 + ci];
  for (int k = 0; k < 64; ++k) {
    const float a = attnS[k * 65 + mloc];
    const float4 wv = *(const float4*)&Wt4[k * 68 + co0];
#pragma unroll
    for (int ci = 0; ci < 4; ++ci)
      acc[ci] = __builtin_fmaf(((const float*)&wv)[ci], a, acc[ci]);
  }
#pragma unroll
  for (int ci = 0; ci < 4; ++ci) {
    const size_t idx = ((size_t)b * 64 + co0 + ci) * 4096 + m0 + mloc;
    out[idx] = lrelu(acc[ci]) + x[idx];
  }
}

extern "C" void kernel_launch(void* const* d_in, const int* in_sizes, int n_in,
                              void* d_out, int out_size, void* d_ws, size_t ws_size,
                              hipStream_t stream) {
  const float* x = (const float*)d_in[0];
  const float* W1 = (const float*)d_in[1];
  const float* b1 = (const float*)d_in[2];
  const float* W2 = (const float*)d_in[3];
  const float* b2 = (const float*)d_in[4];
  const float* W3 = (const float*)d_in[5];
  const float* b3 = (const float*)d_in[6];
  const float* W4 = (const float*)d_in[7];
  const float* b4 = (const float*)d_in[8];
  float* out = (float*)d_out;

  const size_t planes = (size_t)4 * 4096 * 64; // 1M bf16 elems each
  unsigned short* x1t = (unsigned short*)d_ws;
  unsigned short* x2t = x1t + planes;
  unsigned short* x3 = x2t + planes;

  hipLaunchKernelGGL(k1_conv3, dim3(256), dim3(256), 0, stream,
                     x, W1, b1, W2, b2, W3, b3, x1t, x2t, x3);
  hipLaunchKernelGGL(k2_attn_fused, dim3(256), dim3(1024), 0, stream,
                     x1t, x2t, x3, W4, b4, x, out);
}

// Round 18
// 43.963 us; speedup vs baseline: 2.2467x; 1.1598x over previous
//
#include <hip/hip_runtime.h>
#include <hip/hip_bf16.h>
#include <math.h>

using f32x4 = __attribute__((ext_vector_type(4))) float;
using s16x8 = __attribute__((ext_vector_type(8))) short;
using s16x4 = __attribute__((ext_vector_type(4))) short;

#define LOG2E 1.44269504f

__device__ __forceinline__ unsigned short f2bf(float f) {
  unsigned int u = __builtin_bit_cast(unsigned int, f);
  u += 0x7FFFu + ((u >> 16) & 1u);
  return (unsigned short)(u >> 16);
}
__device__ __forceinline__ float lrelu(float v) { return v > 0.f ? v : 0.01f * v; }

// pack two f32 -> one u32 of 2 bf16 (truncation; bias cancels in softmax ratio)
__device__ __forceinline__ unsigned packbf(float lo, float hi) {
  return __builtin_amdgcn_perm(__builtin_bit_cast(unsigned, hi),
                               __builtin_bit_cast(unsigned, lo), 0x07060302u);
}
__device__ __forceinline__ float redsum_lh(float x) {
  x += __shfl_xor(x, 16);
  x += __shfl_xor(x, 32);
  return x;
}

#define GLL16(src, dst)                                                        \
  __builtin_amdgcn_global_load_lds(                                            \
      (const __attribute__((address_space(1))) void*)(src),                    \
      (__attribute__((address_space(3))) void*)(dst), 16, 0, 0)

// ---------------------------------------------------------------------------
// Kernel 1 (MFMA): x1t[n][c], x2t[n][c] (x2 pre-scaled by log2e), and
// x3f = V in PV-A-fragment PHYSICAL layout:
//   x3f[b][tile(32n)][row r:32][phys p:8][16B], 4KB/tile. Chunk (r,p) holds
//   cid = p^(r&7): c = r + 32*(cid>>2), h = cid&3, elems i=0..7 ->
//   n = tile*32 + (i<4 ? h*4+i : 16+h*4+(i-4)).
// grid 256 = (b:4, ntile:64 [64n]), block 256 = 4 waves. (R17-proven core)
// ---------------------------------------------------------------------------
#define K1_W 8192
#define K1_X3 32768
#define K1_SM 41984

__global__ __launch_bounds__(256) void k1_conv3(
    const float* __restrict__ x,
    const float* __restrict__ W1, const float* __restrict__ b1,
    const float* __restrict__ W2, const float* __restrict__ b2,
    const float* __restrict__ W3, const float* __restrict__ b3,
    unsigned short* __restrict__ x1t, unsigned short* __restrict__ x2t,
    unsigned short* __restrict__ x3f) {
  __shared__ __align__(16) char SM[K1_SM];
  char* smB = (char*)SM;
  const int t = threadIdx.x;
  const int b = blockIdx.x >> 6;
  const int n0 = (blockIdx.x & 63) << 6;
  const int lane = t & 63, wave = t >> 6; // wave = nj (16-n strip)
  const int l15 = lane & 15, lh = lane >> 4;
  const int swz = (l15 & 7) << 4;

  // ---- stage W1..3 -> Wb bf16, XOR-swizzled rows (one-time)
  const float* Ws[3] = {W1, W2, W3};
  char* Wb = smB + K1_W;
#pragma unroll
  for (int w = 0; w < 3; ++w)
#pragma unroll
    for (int it = 0; it < 4; ++it) {
      const int c = t >> 2, k4 = (t & 3) * 16 + it * 4;
      const float4 wv = *(const float4*)(Ws[w] + c * 64 + k4);
      char* dst = Wb + w * 8192 + c * 128 + ((k4 * 2) ^ ((c & 7) << 4));
      *(unsigned*)dst = packbf(wv.x, wv.y);
      *(unsigned*)(dst + 4) = packbf(wv.z, wv.w);
    }
  // ---- stage XT[n][k] bf16, XOR-swizzled (transpose of x tile)
  char* XT = smB;
#pragma unroll
  for (int it = 0; it < 4; ++it) {
    const int k = (t >> 4) + it * 16, n4 = (t & 15) * 4;
    const float4 xv = *(const float4*)(x + ((size_t)b * 64 + k) * 4096 + n0 + n4);
#pragma unroll
    for (int j = 0; j < 4; ++j) {
      const int n = n4 + j;
      *(unsigned short*)(XT + n * 128 + ((k * 2) ^ ((n & 7) << 4))) =
          f2bf(((const float*)&xv)[j]);
    }
  }
  __syncthreads();

  // ---- B-frags for my n-strip (n = wave*16 + l15)
  s16x8 bf0, bf1;
  {
    const char* xr = XT + (wave * 16 + l15) * 128;
    bf0 = *(const s16x8*)(xr + ((lh * 16) ^ swz));
    bf1 = *(const s16x8*)(xr + ((lh * 16 + 64) ^ swz));
  }
  // ---- 3 convs x 4 c-tiles: MFMA (bias in C) -> lrelu -> store
  char* sX3 = smB + K1_X3; // [64][72] bf16 (144B rows)
#pragma unroll
  for (int w = 0; w < 3; ++w) {
    const float* bb = (w == 0) ? b1 : (w == 1) ? b2 : b3;
#pragma unroll
    for (int ci = 0; ci < 4; ++ci) {
      f32x4 acc = *(const f32x4*)(bb + ci * 16 + lh * 4); // C = bias (row=lh*4+r)
      const char* wr = Wb + w * 8192 + (ci * 16 + l15) * 128;
      const s16x8 af0 = *(const s16x8*)(wr + ((lh * 16) ^ swz));
      const s16x8 af1 = *(const s16x8*)(wr + ((lh * 16 + 64) ^ swz));
      acc = __builtin_amdgcn_mfma_f32_16x16x32_bf16(af0, bf0, acc, 0, 0, 0);
      acc = __builtin_amdgcn_mfma_f32_16x16x32_bf16(af1, bf1, acc, 0, 0, 0);
      float v[4];
#pragma unroll
      for (int r = 0; r < 4; ++r) v[r] = lrelu(acc[r]);
      if (w == 1)
#pragma unroll
        for (int r = 0; r < 4; ++r) v[r] *= LOG2E;
      if (w < 2) {
        unsigned pk[2] = {packbf(v[0], v[1]), packbf(v[2], v[3])};
        unsigned short* base = (w ? x2t : x1t);
        unsigned short* dst =
            base + ((size_t)b * 4096 + n0 + wave * 16 + l15) * 64 + ci * 16 + lh * 4;
        *(uint2*)dst = *(const uint2*)pk;
      } else {
#pragma unroll
        for (int r = 0; r < 4; ++r)
          *(unsigned short*)(sX3 + (ci * 16 + lh * 4 + r) * 144 +
                             (wave * 16 + l15) * 2) = f2bf(v[r]);
      }
    }
  }
  __syncthreads();
  // ---- x3f phys store: thread -> 2 chunks e over [tile_l:2][r:32][p:8]
  {
    char* x3fB = (char*)x3f;
#pragma unroll
    for (int u = 0; u < 2; ++u) {
      const int e = t * 2 + u;
      const int p8 = e & 7, r = (e >> 3) & 31, tl = e >> 8;
      const int cid = p8 ^ (r & 7);
      const int c = r + 32 * (cid >> 2);
      const int h = cid & 3;
      s16x8 v;
#pragma unroll
      for (int i = 0; i < 4; ++i) {
        v[i] = *(const short*)(sX3 + c * 144 + (tl * 32 + h * 4 + i) * 2);
        v[i + 4] = *(const short*)(sX3 + c * 144 + (tl * 32 + 16 + h * 4 + i) * 2);
      }
      const size_t tile = (size_t)b * 128 + (n0 >> 5) + tl;
      *(s16x8*)(x3fB + ((tile * 32 + r) * 8 + p8) * 16) = v;
    }
  }
}

// ---------------------------------------------------------------------------
// Kernel 2: R9 structure verbatim, with (a) V-read in K-identical conflict-free
// form via x3f phys layout, (b) R12-proven transpose-free PV (NO xswaps),
// (c) XCD-aware bid swizzle (2 XCDs/batch -> K/V L2-resident).
// grid 256 = (b, mtile64). block 1024 = 16 waves = msub(2: 32m) x split(8: 512n).
// K,V DOUBLE-buffered; ONE barrier per step.
// ---------------------------------------------------------------------------
#define KOFF 0
#define VOFF 65536
#define W4OFF 131072
#define SLOFF 148480
#define SMSZ 150528

__global__ __launch_bounds__(1024) void k2_attn_fused(
    const unsigned short* __restrict__ x1t,
    const unsigned short* __restrict__ x2t,
    const unsigned short* __restrict__ x3f,
    const float* __restrict__ W4, const float* __restrict__ b4,
    const float* __restrict__ x, float* __restrict__ out) {
  __shared__ __align__(16) char SM[SMSZ];
  char* smB = (char*)SM;

  const int t = threadIdx.x;
  const int wave = t >> 6, lane = t & 63;
  const int l15 = lane & 15, lh = lane >> 4;
  const int msub = wave & 1, split = wave >> 1; // split 0..7
  const int bid = ((blockIdx.x & 7) << 5) | (blockIdx.x >> 3); // XCD swizzle
  const int b = bid >> 6;
  const int m0 = (bid & 63) << 6;
  const int nb = split * 512;

  const char* x1B = (const char*)(x1t + (size_t)b * 4096 * 64); // [n][c] rows 128B
  const char* x3B = (const char*)x3f + (size_t)b * 524288;      // [128 tiles][4KB]
  const unsigned short* x2b = x2t + (size_t)b * 4096 * 64;

  // W4 -> LDS transposed (region disjoint from K/V; loaded once)
  {
    float* Wt4 = (float*)(smB + W4OFF);
    for (int e = t; e < 4096; e += 1024) Wt4[(e & 63) * 68 + (e >> 6)] = W4[e];
  }

  // staging offsets: K pre-swizzled src (R9); V phys-in-global -> LINEAR src
  int kSrcOff[2], vSrcOff[2];
  char *kDst[2], *vDst[2];
#pragma unroll
  for (int i = 0; i < 2; ++i) {
    const int o = msub * 2048 + i * 1024 + lane * 16;
    {
      const int n = o >> 7, cb = (o & 127) ^ ((n & 7) << 4);
      kSrcOff[i] = n * 128 + cb;
      kDst[i] = smB + KOFF + split * 4096 + msub * 2048 + i * 1024;
    }
    vSrcOff[i] = o; // linear copy: global already holds phys layout
    vDst[i] = smB + VOFF + split * 4096 + msub * 2048 + i * 1024;
  }

  // Q fragments (B-operand), persistent
  s16x8 qf[2][2];
#pragma unroll
  for (int q2 = 0; q2 < 2; ++q2) {
    const unsigned short* qp = x2b + (size_t)(m0 + msub * 32 + q2 * 16 + l15) * 64 + lh * 8;
    qf[q2][0] = *(const s16x8*)qp;
    qf[q2][1] = *(const s16x8*)(qp + 32);
  }

  f32x4 O[2][4];
#pragma unroll
  for (int q2 = 0; q2 < 2; ++q2)
#pragma unroll
    for (int s = 0; s < 4; ++s) O[q2][s] = (f32x4){0.f, 0.f, 0.f, 0.f};
  float l_part[2] = {0.f, 0.f};

  const int swzK = (l15 & 7) << 4;

  // prologue: stage tile 0 into buffer 0
#pragma unroll
  for (int i = 0; i < 2; ++i) {
    GLL16(x1B + (size_t)nb * 128 + kSrcOff[i], kDst[i]);
    GLL16(x3B + (size_t)(nb >> 5) * 4096 + vSrcOff[i], vDst[i]);
  }
  __syncthreads();

  for (int j = 0; j < 16; ++j) {
    const int p = j & 1;
    // ---- stage next tile into the other buffer (drained by this step's barrier)
    if (j < 15) {
      const int nstep = nb + (j + 1) * 32;
      const int po = (p ^ 1) * 32768;
#pragma unroll
      for (int i = 0; i < 2; ++i) {
        GLL16(x1B + (size_t)nstep * 128 + kSrcOff[i], kDst[i] + po);
        GLL16(x3B + (size_t)(nstep >> 5) * 4096 + vSrcOff[i], vDst[i] + po);
      }
    }
    // ---- LDS fragment reads (K + V, buffer p) — both conflict-free form
    s16x8 kf[2][2], vf[4];
#pragma unroll
    for (int s2 = 0; s2 < 2; ++s2) {
      const char* kp = smB + KOFF + p * 32768 + split * 4096 + (s2 * 16 + l15) * 128;
      kf[s2][0] = *(const s16x8*)(kp + ((lh * 16) ^ swzK));
      kf[s2][1] = *(const s16x8*)(kp + ((lh * 16 + 64) ^ swzK));
    }
    const char* vp = smB + VOFF + p * 32768 + split * 4096;
#pragma unroll
    for (int s = 0; s < 4; ++s)
      vf[s] = *(const s16x8*)(vp + ((s & 1) * 16 + l15) * 128 +
                              (((s >> 1) * 64 + lh * 16) ^ swzK));
    // ---- QK: S[q2][s2], n on (s2, lh, r), m on l15
    f32x4 S[2][2];
#pragma unroll
    for (int q2 = 0; q2 < 2; ++q2)
#pragma unroll
      for (int s2 = 0; s2 < 2; ++s2) {
        f32x4 z = {0.f, 0.f, 0.f, 0.f};
        z = __builtin_amdgcn_mfma_f32_16x16x32_bf16(kf[s2][0], qf[q2][0], z, 0, 0, 0);
        S[q2][s2] = __builtin_amdgcn_mfma_f32_16x16x32_bf16(kf[s2][1], qf[q2][1], z, 0, 0, 0);
      }
    // ---- softmax (no-max exp2) -> k-permuted pf (R12-proven; NO cross-lane)
    s16x8 pf[2];
#pragma unroll
    for (int q2 = 0; q2 < 2; ++q2) {
      float pr[2][4];
      float ts = 0.f;
#pragma unroll
      for (int s2 = 0; s2 < 2; ++s2)
#pragma unroll
        for (int r = 0; r < 4; ++r) {
          pr[s2][r] = __builtin_amdgcn_exp2f(S[q2][s2][r]);
          ts += pr[s2][r];
        }
      l_part[q2] += ts;
      int4 pw = {(int)packbf(pr[0][0], pr[0][1]), (int)packbf(pr[0][2], pr[0][3]),
                 (int)packbf(pr[1][0], pr[1][1]), (int)packbf(pr[1][2], pr[1][3])};
      pf[q2] = __builtin_bit_cast(s16x8, pw);
    }
    // ---- PV (k-permuted A=V frags match pf slot-for-slot)
#pragma unroll
    for (int q2 = 0; q2 < 2; ++q2)
#pragma unroll
      for (int s = 0; s < 4; ++s)
        O[q2][s] = __builtin_amdgcn_mfma_f32_16x16x32_bf16(vf[s], pf[q2], O[q2][s], 0, 0, 0);
    __syncthreads(); // one barrier/step: syncs reads of buf p + drains staging
  }

  // ---- epilogue 1: l reduce (once) + publish fp32 partials over dead K/V
  float* cOf = (float*)smB;           // [16][32][64] = 128KB, overlays K+V
  float* sLf = (float*)(smB + SLOFF); // [16][32]
#pragma unroll
  for (int q2 = 0; q2 < 2; ++q2) {
    const float l = redsum_lh(l_part[q2]);
    const int m32 = q2 * 16 + l15;
    if (lh == 0) sLf[wave * 32 + m32] = l;
#pragma unroll
    for (int s = 0; s < 4; ++s)
      *(f32x4*)(cOf + wave * 2048 + m32 * 64 + s * 16 + lh * 4) = O[q2][s];
  }
  __syncthreads();

  // ---- epilogue 2: merge 8 splits (plain sums). thread -> m=t&63, cq=t>>6
  const int mloc = t & 63, cq = t >> 6;
  const int msub2 = mloc >> 5, m32b = mloc & 31;
  float den = 0.f, num[4] = {0.f, 0.f, 0.f, 0.f};
#pragma unroll
  for (int s2 = 0; s2 < 8; ++s2) {
    const int w = msub2 + 2 * s2;
    den += sLf[w * 32 + m32b];
    const f32x4 cv = *(const f32x4*)(cOf + w * 2048 + m32b * 64 + cq * 4);
#pragma unroll
    for (int jj = 0; jj < 4; ++jj) num[jj] += cv[jj];
  }
  const float inv = 1.f / den;
  __syncthreads(); // cO reads done -> safe to overlay attnS
  float* attnS = (float*)smB; // [64][65]
#pragma unroll
  for (int jj = 0; jj < 4; ++jj) attnS[(cq * 4 + jj) * 65 + mloc] = num[jj] * inv;
  __syncthreads();

  // ---- epilogue 3: out = lrelu(W4 @ attn + b4) + x
  const float* Wt4 = (const float*)(smB + W4OFF); // [64][68]
  const int co0 = cq * 4;
  float acc[4];
#pragma unroll
  for (int ci = 0; ci < 4; ++ci) acc[ci] = b4[co0 + ci];
  for (int k = 0; k < 64; ++k) {
    const float a = attnS[k * 65 + mloc];
    const float4 wv = *(const float4*)&Wt4[k * 68 + co0];
#pragma unroll
    for (int ci = 0; ci < 4; ++ci)
      acc[ci] = __builtin_fmaf(((const float*)&wv)[ci], a, acc[ci]);
  }
#pragma unroll
  for (int ci = 0; ci < 4; ++ci) {
    const size_t idx = ((size_t)b * 64 + co0 + ci) * 4096 + m0 + mloc;
    out[idx] = lrelu(acc[ci]) + x[idx];
  }
}

extern "C" void kernel_launch(void* const* d_in, const int* in_sizes, int n_in,
                              void* d_out, int out_size, void* d_ws, size_t ws_size,
                              hipStream_t stream) {
  const float* x = (const float*)d_in[0];
  const float* W1 = (const float*)d_in[1];
  const float* b1 = (const float*)d_in[2];
  const float* W2 = (const float*)d_in[3];
  const float* b2 = (const float*)d_in[4];
  const float* W3 = (const float*)d_in[5];
  const float* b3 = (const float*)d_in[6];
  const float* W4 = (const float*)d_in[7];
  const float* b4 = (const float*)d_in[8];
  float* out = (float*)d_out;

  const size_t planes = (size_t)4 * 4096 * 64; // 1M bf16 elems each
  unsigned short* x1t = (unsigned short*)d_ws;
  unsigned short* x2t = x1t + planes;
  unsigned short* x3f = x2t + planes; // phys V layout, 4*512KB = 2MB

  hipLaunchKernelGGL(k1_conv3, dim3(256), dim3(256), 0, stream,
                     x, W1, b1, W2, b2, W3, b3, x1t, x2t, x3f);
  hipLaunchKernelGGL(k2_attn_fused, dim3(256), dim3(1024), 0, stream,
                     x1t, x2t, x3f, W4, b4, x, out);
}